// Round 1
// baseline (13785.367 us; speedup 1.0000x reference)
//
#include <hip/hip_runtime.h>
#include <math.h>

// Griffin-Lim inversion of a log-magnitude spectrogram.
// B=128 batches, F=256 frames, 128 rfft bins (N_FFT=254), HOP=64, 50 iterations.
// DFT expressed as GEMM: forward Wf[254x256] (win folded in), inverse Wi[256x254]
// (a_k/254 and synthesis window folded in). Overlap-add done as a gather
// (deterministic, no float atomics).

#define B_SZ 128
#define NFRM 256
#define BINS 128
#define NFFT 254
#define HOPS 64
#define OUTL 16574
#define AUD  16384
#define WFS  16576          // padded per-batch waveform stride
#define MT   64             // frames per GEMM block
#define KT   16             // K chunk
#define GL_ITERS 50
#define MAXV 69.37411499023438f
#define PI2f 6.2831853071795864f

// ---------------------------------------------------------------- tables ----
__global__ void tables_k(float* __restrict__ Wf, float* __restrict__ Wi,
                         unsigned* __restrict__ gmax) {
  int tid = blockIdx.x * blockDim.x + threadIdx.x;
  int stride = gridDim.x * blockDim.x;
  if (blockIdx.x == 0 && threadIdx.x == 0) *gmax = 0u;

  // Forward: Wf[n][j], n=0..255 (rows 254,255 zero), j=2k -> win[n]*cos(2pi k n/254),
  // j=2k+1 -> -win[n]*sin(...)   (rfft: X = sum x*win*exp(-i...))
  for (int i = tid; i < 256 * 256; i += stride) {
    int n = i >> 8, j = i & 255, k = j >> 1;
    float v = 0.f;
    if (n < NFFT) {
      int m = (k * n) % NFFT;                      // exact angle reduction
      float ang = PI2f * (float)m / (float)NFFT;
      float wn = 0.5f - 0.5f * cosf(PI2f * (float)n / (float)NFFT);  // periodic hann
      v = wn * ((j & 1) ? -sinf(ang) : cosf(ang));
    }
    Wf[i] = v;
  }
  // Inverse: Wi[j][n], j=2k -> swin[n]*(a_k/254)*cos, j=2k+1 -> -swin[n]*(a_k/254)*sin
  // (cols 254,255 zero). a_0=a_127=1, else 2.  irfft ignores imag of bins 0/127 -> exact.
  for (int i = tid; i < 256 * 256; i += stride) {
    int j = i >> 8, n = i & 255, k = j >> 1;
    float v = 0.f;
    if (n < NFFT) {
      int m = (k * n) % NFFT;
      float ang = PI2f * (float)m / (float)NFFT;
      float wn = 0.5f - 0.5f * cosf(PI2f * (float)n / (float)NFFT);
      // synth window: swin[n] = win[n] / sum_q win^2[(n&63)+64q]
      float d = 0.f;
      int p = n & 63;
      for (int q = 0; q < 4; ++q) {
        int nn = p + 64 * q;
        if (nn < NFFT) { float w = 0.5f - 0.5f * cosf(PI2f * (float)nn / (float)NFFT); d += w * w; }
      }
      float sw = wn / d;
      float ak = (k == 0 || k == BINS - 1) ? 1.f : 2.f;
      v = sw * (ak / (float)NFFT) * ((j & 1) ? -sinf(ang) : cosf(ang));
    }
    Wi[i] = v;
  }
}

// ------------------------------------------------------------------- mag ----
// mag = exp(5*(x-1))*MAXV ; also initialize spec S = (mag, 0) for iteration 0.
__global__ void mag_k(const float* __restrict__ x, float* __restrict__ mag,
                      float* __restrict__ S) {
  int i = blockIdx.x * 256 + threadIdx.x;          // exact: B*F*BINS = 4194304
  float v = expf(5.f * (x[i] - 1.f)) * MAXV;
  mag[i] = v;
  size_t m = (size_t)(i >> 7);
  int k = i & 127;
  S[(m << 8) + 2 * k]     = v;
  S[(m << 8) + 2 * k + 1] = 0.f;
}

// ---------------------------------------------------- GEMM1: STFT+modify ----
// grid 512: block = (b, f0) covering 64 frames. A generated from wf in LDS.
__global__ __launch_bounds__(256) void gemm1_k(const float* __restrict__ wf,
    const float* __restrict__ Wf, const float* __restrict__ mag,
    float* __restrict__ S) {
  __shared__ float wfs[4288];                      // (MT-1)*HOP + 254 = 4286 (+pad)
  __shared__ float Bl[KT][256];
  int blk = blockIdx.x;
  int b = blk >> 2, f0 = (blk & 3) * MT;
  const float* wfb = wf + (size_t)b * WFS + f0 * HOPS;
  int tid = threadIdx.x, lane = tid & 63, wv = tid >> 6;

  for (int i = tid; i < 4286; i += 256) wfs[i] = wfb[i];
  if (tid == 0) { wfs[4286] = 0.f; wfs[4287] = 0.f; }   // K padded to 256; Wf rows 254/255 are zero

  float acc[16][4];
#pragma unroll
  for (int i = 0; i < 16; ++i) { acc[i][0] = acc[i][1] = acc[i][2] = acc[i][3] = 0.f; }
  __syncthreads();

  for (int kk = 0; kk < 256; kk += KT) {
    __syncthreads();
    const float4* src = (const float4*)(Wf + ((size_t)kk << 8));
    float4* dst = (float4*)&Bl[0][0];
#pragma unroll
    for (int q = 0; q < 4; ++q) dst[tid + 256 * q] = src[tid + 256 * q];
    __syncthreads();
#pragma unroll
    for (int t4 = 0; t4 < KT; t4 += 4) {
      float4 b0 = *(const float4*)&Bl[t4 + 0][lane << 2];
      float4 b1 = *(const float4*)&Bl[t4 + 1][lane << 2];
      float4 b2 = *(const float4*)&Bl[t4 + 2][lane << 2];
      float4 b3 = *(const float4*)&Bl[t4 + 3][lane << 2];
#pragma unroll
      for (int i2 = 0; i2 < 16; ++i2) {
        float4 a4 = *(const float4*)&wfs[((wv << 4) + i2) * HOPS + kk + t4];  // wave-broadcast
        acc[i2][0] += a4.x * b0.x + a4.y * b1.x + a4.z * b2.x + a4.w * b3.x;
        acc[i2][1] += a4.x * b0.y + a4.y * b1.y + a4.z * b2.y + a4.w * b3.y;
        acc[i2][2] += a4.x * b0.z + a4.y * b1.z + a4.z * b2.z + a4.w * b3.z;
        acc[i2][3] += a4.x * b0.w + a4.y * b1.w + a4.z * b2.w + a4.w * b3.w;
      }
    }
  }

  // epilogue: spec = mag * X / |X|   (lane owns bins k = 2*lane, 2*lane+1)
#pragma unroll
  for (int i2 = 0; i2 < 16; ++i2) {
    int fr = f0 + (wv << 4) + i2;
    const float2* mp = (const float2*)(mag + ((size_t)b * NFRM + fr) * BINS);
    float2 mg = mp[lane];
    float re0 = acc[i2][0], im0 = acc[i2][1], re1 = acc[i2][2], im1 = acc[i2][3];
    float s0 = re0 * re0 + im0 * im0;
    float s1 = re1 * re1 + im1 * im1;
    if (s0 == 0.f) { re0 = 1.f; s0 = 1.f; }      // angle(0)=0 -> spec=(mag,0)
    if (s1 == 0.f) { re1 = 1.f; s1 = 1.f; }
    float r0 = mg.x * rsqrtf(s0);
    float r1 = mg.y * rsqrtf(s1);
    float4 o = make_float4(re0 * r0, im0 * r0, re1 * r1, im1 * r1);
    *(float4*)(S + (((size_t)b * NFRM + fr) << 8) + (lane << 2)) = o;
  }
}

// --------------------------------------------------------- GEMM2: iSTFT -----
// FR[m][n] = sum_j S[m][j] * Wi[j][n]   (synth window folded in Wi)
__global__ __launch_bounds__(256) void gemm2_k(const float* __restrict__ S,
    const float* __restrict__ Wi, float* __restrict__ FR) {
  __shared__ float Al[MT][KT];
  __shared__ float Bl[KT][256];
  int row0 = blockIdx.x * MT;
  int tid = threadIdx.x, lane = tid & 63, wv = tid >> 6;

  float acc[16][4];
#pragma unroll
  for (int i = 0; i < 16; ++i) { acc[i][0] = acc[i][1] = acc[i][2] = acc[i][3] = 0.f; }

  for (int kk = 0; kk < 256; kk += KT) {
    __syncthreads();
    {
      int m = tid >> 2, c4 = (tid & 3) << 2;
      *(float4*)&Al[m][c4] = *(const float4*)(S + (((size_t)(row0 + m)) << 8) + kk + c4);
      const float4* src = (const float4*)(Wi + ((size_t)kk << 8));
      float4* dst = (float4*)&Bl[0][0];
#pragma unroll
      for (int q = 0; q < 4; ++q) dst[tid + 256 * q] = src[tid + 256 * q];
    }
    __syncthreads();
#pragma unroll
    for (int t4 = 0; t4 < KT; t4 += 4) {
      float4 b0 = *(const float4*)&Bl[t4 + 0][lane << 2];
      float4 b1 = *(const float4*)&Bl[t4 + 1][lane << 2];
      float4 b2 = *(const float4*)&Bl[t4 + 2][lane << 2];
      float4 b3 = *(const float4*)&Bl[t4 + 3][lane << 2];
#pragma unroll
      for (int i2 = 0; i2 < 16; ++i2) {
        float4 a4 = *(const float4*)&Al[(wv << 4) + i2][t4];                 // wave-broadcast
        acc[i2][0] += a4.x * b0.x + a4.y * b1.x + a4.z * b2.x + a4.w * b3.x;
        acc[i2][1] += a4.x * b0.y + a4.y * b1.y + a4.z * b2.y + a4.w * b3.y;
        acc[i2][2] += a4.x * b0.z + a4.y * b1.z + a4.z * b2.z + a4.w * b3.z;
        acc[i2][3] += a4.x * b0.w + a4.y * b1.w + a4.z * b2.w + a4.w * b3.w;
      }
    }
  }
#pragma unroll
  for (int i2 = 0; i2 < 16; ++i2) {
    *(float4*)(FR + (((size_t)(row0 + (wv << 4) + i2)) << 8) + (lane << 2)) =
        make_float4(acc[i2][0], acc[i2][1], acc[i2][2], acc[i2][3]);
  }
}

// ----------------------------------------------------------- overlap-add ----
// wf[b][t] = sum over frames f covering t of FR[b][f][t-64f]  (gather, <=4 terms)
__global__ void oa_k(const float* __restrict__ FR, float* __restrict__ wf) {
  int b = blockIdx.y, t = blockIdx.x * 256 + threadIdx.x;
  if (t >= OUTL) return;
  int f_hi = t >> 6; if (f_hi > NFRM - 1) f_hi = NFRM - 1;
  int f_lo = (t >= NFFT) ? (((t - NFFT) >> 6) + 1) : 0;
  const float* FRb = FR + ((size_t)b * NFRM << 8);
  float s = 0.f;
  for (int f = f_lo; f <= f_hi; ++f) s += FRb[(f << 8) + t - (f << 6)];
  wf[(size_t)b * WFS + t] = s;
}

// ------------------------------------------------------------- reductions ---
__global__ void redmax_k(const float* __restrict__ wf, unsigned* __restrict__ gmax) {
  int b = blockIdx.y, t = blockIdx.x * 256 + threadIdx.x;
  float v = 0.f;
  if (t < OUTL) v = fabsf(wf[(size_t)b * WFS + t]);
#pragma unroll
  for (int o = 32; o > 0; o >>= 1) v = fmaxf(v, __shfl_xor(v, o, 64));
  if ((threadIdx.x & 63) == 0) atomicMax(gmax, __float_as_uint(v));  // nonneg floats: uint order == float order
}

__global__ void out_k(const float* __restrict__ wf, const unsigned* __restrict__ gmax,
                      float* __restrict__ out) {
  int b = blockIdx.y, t = blockIdx.x * 256 + threadIdx.x;   // t < 16384 exact
  float g = __uint_as_float(*gmax);
  out[(size_t)b * AUD + t] = wf[(size_t)b * WFS + t] / g;
}

// ---------------------------------------------------------------- launch ----
extern "C" void kernel_launch(void* const* d_in, const int* in_sizes, int n_in,
                              void* d_out, int out_size, void* d_ws, size_t ws_size,
                              hipStream_t stream) {
  const float* x = (const float*)d_in[0];

  float* ws  = (float*)d_ws;
  float* wf  = ws;                                  // 128*16576      = 2,121,728 f
  float* mag = wf  + (size_t)B_SZ * WFS;            // 128*256*128    = 4,194,304 f
  float* S   = mag + (size_t)B_SZ * NFRM * BINS;    // 128*256*256    = 8,388,608 f
  float* FR  = S   + (size_t)B_SZ * NFRM * 256;     // 128*256*256    = 8,388,608 f
  float* Wf  = FR  + (size_t)B_SZ * NFRM * 256;     // 256*256        = 65,536 f
  float* Wi  = Wf  + 65536;                         // 256*256        = 65,536 f
  unsigned* gmax = (unsigned*)(Wi + 65536);         // 1
  // total ~93 MB of d_ws

  tables_k<<<64, 256, 0, stream>>>(Wf, Wi, gmax);
  mag_k<<<16384, 256, 0, stream>>>(x, mag, S);

  // initial reconstruction: istft of (mag, 0)
  gemm2_k<<<512, 256, 0, stream>>>(S, Wi, FR);
  oa_k<<<dim3(65, B_SZ), 256, 0, stream>>>(FR, wf);

  for (int it = 0; it < GL_ITERS; ++it) {
    gemm1_k<<<512, 256, 0, stream>>>(wf, Wf, mag, S);
    gemm2_k<<<512, 256, 0, stream>>>(S, Wi, FR);
    oa_k<<<dim3(65, B_SZ), 256, 0, stream>>>(FR, wf);
  }

  redmax_k<<<dim3(65, B_SZ), 256, 0, stream>>>(wf, gmax);
  out_k<<<dim3(64, B_SZ), 256, 0, stream>>>(wf, gmax, (float*)d_out);
}